// Round 17
// baseline (245.909 us; speedup 1.0000x reference)
//
#include <hip/hip_runtime.h>
#include <math.h>

#define CS 256
#define CZ 128
#define HEADS 8
#define DH 32
#define SDIM 128
#define RDIM 256
#define MROWS (SDIM*RDIM)   // 32768
#define ZROWS (RDIM*RDIM)   // 65536
#define EPSF 1e-5f
#define LOG2E 1.44269504088896340736f

typedef __attribute__((ext_vector_type(8))) short short8_t;   // 8 bf16 (4 VGPRs)
typedef __attribute__((ext_vector_type(4))) float f32x4;

__device__ __forceinline__ float waveReduceSum(float v) {
    #pragma unroll
    for (int off = 32; off > 0; off >>= 1) v += __shfl_xor(v, off, 64);
    return v;
}

__device__ __forceinline__ unsigned short f2bf(float f) {
    unsigned u = __float_as_uint(f);
    unsigned r = (u + 0x7fffu + ((u >> 16) & 1u)) >> 16;   // RNE
    return (unsigned short)r;
}

__device__ __forceinline__ float bf2f(unsigned short u) {
    return __uint_as_float(((unsigned)u) << 16);
}

// fast packed-bf16 -> f32 unpack (1 op each)
__device__ __forceinline__ float bflo(unsigned u) { return __uint_as_float(u << 16); }
__device__ __forceinline__ float bfhi(unsigned u) { return __uint_as_float(u & 0xffff0000u); }

// packed bf16 convert: lo = a, hi = b (HW RNE, 1 instruction)
__device__ __forceinline__ unsigned cvt_pk_bf16(float a, float b) {
    unsigned r;
    asm("v_cvt_pk_bf16_f32 %0, %1, %2" : "=v"(r) : "v"(a), "v"(b));
    return r;
}

// ---------------- LayerNorm of s: one wave per row of 256, bf16 out ------
__global__ __launch_bounds__(256) void ln_s_kernel(const float* __restrict__ s,
        const float* __restrict__ w, const float* __restrict__ b,
        unsigned short* __restrict__ snb) {
    int wid = threadIdx.x >> 6;
    int lane = threadIdx.x & 63;
    int row = blockIdx.x * 4 + wid;              // < 32768
    const float4 v = ((const float4*)(s + (size_t)row * CS))[lane];
    float sum = waveReduceSum(v.x + v.y + v.z + v.w);
    float sq  = waveReduceSum(v.x*v.x + v.y*v.y + v.z*v.z + v.w*v.w);
    float mean = sum * (1.f/CS);
    float var  = sq * (1.f/CS) - mean*mean;
    float rstd = rsqrtf(var + EPSF);
    const float4 wv = ((const float4*)w)[lane];
    const float4 bv = ((const float4*)b)[lane];
    ushort4 o;
    o.x = f2bf((v.x-mean)*rstd*wv.x + bv.x);
    o.y = f2bf((v.y-mean)*rstd*wv.y + bv.y);
    o.z = f2bf((v.z-mean)*rstd*wv.z + bv.z);
    o.w = f2bf((v.w-mean)*rstd*wv.w + bv.w);
    ((ushort4*)(snb + (size_t)row * CS))[lane] = o;
}

// ------- LayerNorm of z + pair bias via MFMA: block = 64 z-rows ----------
__global__ __launch_bounds__(256) void ln_z_pb_kernel(const float* __restrict__ z,
        const float* __restrict__ w, const float* __restrict__ b,
        const float* __restrict__ wz, unsigned short* __restrict__ pb) {
    __shared__ unsigned short Pol[8][64];
    const int tid = threadIdx.x;
    const int lane = tid & 63, wid = tid >> 6;
    const int ln15 = lane & 15, g = lane >> 4;
    const int base = blockIdx.x * 64;
    const int row = base + wid*16 + ln15;
    const float* zr = z + (size_t)row * CZ;

    // ---- A-frags: wz^T bf16 (row=h=ln15, zero for h>=8) ----
    short8_t wzf[4];
    #pragma unroll
    for (int kk = 0; kk < 4; kk++) {
        short8_t f;
        #pragma unroll
        for (int j = 0; j < 8; j++) {
            float vv = (ln15 < 8) ? wz[(size_t)(kk*32 + g*8 + j)*HEADS + ln15] : 0.f;
            f[j] = (short)f2bf(vv);
        }
        wzf[kk] = f;
    }
    // ---- load z (full-line: 4 g-lanes cover 128B per (row,kk)) ----
    float zv[4][8];
    float sum = 0.f, sq = 0.f;
    #pragma unroll
    for (int kk = 0; kk < 4; kk++) {
        float4 a0 = *(const float4*)&zr[kk*32 + g*8];
        float4 a1 = *(const float4*)&zr[kk*32 + g*8 + 4];
        zv[kk][0]=a0.x; zv[kk][1]=a0.y; zv[kk][2]=a0.z; zv[kk][3]=a0.w;
        zv[kk][4]=a1.x; zv[kk][5]=a1.y; zv[kk][6]=a1.z; zv[kk][7]=a1.w;
        #pragma unroll
        for (int j = 0; j < 8; j++) { sum += zv[kk][j]; sq = fmaf(zv[kk][j], zv[kk][j], sq); }
    }
    sum += __shfl_xor(sum, 16, 64); sum += __shfl_xor(sum, 32, 64);
    sq  += __shfl_xor(sq, 16, 64);  sq  += __shfl_xor(sq, 32, 64);
    float mean = sum * (1.f/CZ);
    float var  = sq * (1.f/CZ) - mean*mean;
    float rstd = rsqrtf(var + EPSF);
    float mr = mean * rstd;
    // ---- zn B-frags (col=ln15=row-idx, k=g*8.. within each kk) ----
    short8_t znf[4];
    #pragma unroll
    for (int kk = 0; kk < 4; kk++) {
        float4 w0 = *(const float4*)&w[kk*32 + g*8];
        float4 w1 = *(const float4*)&w[kk*32 + g*8 + 4];
        float4 b0 = *(const float4*)&b[kk*32 + g*8];
        float4 b1 = *(const float4*)&b[kk*32 + g*8 + 4];
        float wl[8] = {w0.x,w0.y,w0.z,w0.w,w1.x,w1.y,w1.z,w1.w};
        float bl[8] = {b0.x,b0.y,b0.z,b0.w,b1.x,b1.y,b1.z,b1.w};
        unsigned pk[4];
        #pragma unroll
        for (int e = 0; e < 4; e++) {
            float n0 = fmaf(fmaf(zv[kk][e*2+0], rstd, -mr), wl[e*2+0], bl[e*2+0]);
            float n1 = fmaf(fmaf(zv[kk][e*2+1], rstd, -mr), wl[e*2+1], bl[e*2+1]);
            pk[e] = cvt_pk_bf16(n0, n1);
        }
        znf[kk] = *(short8_t*)pk;
    }
    // ---- pb = wz^T . zn^T ----
    f32x4 acc = (f32x4){0.f,0.f,0.f,0.f};
    #pragma unroll
    for (int kk = 0; kk < 4; kk++)
        acc = __builtin_amdgcn_mfma_f32_16x16x32_bf16(wzf[kk], znf[kk], acc, 0, 0, 0);
    // ---- bounce to LDS, coalesced store: pb[h][base..base+63] ----
    if (g < 2) {
        #pragma unroll
        for (int r = 0; r < 4; r++)
            Pol[g*4 + r][wid*16 + ln15] = f2bf(acc[r]);
    }
    __syncthreads();
    if (tid < 64) {
        int h = tid >> 3, seg = tid & 7;
        *(uint4*)&pb[(size_t)h*ZROWS + base + seg*8] = *(uint4*)&Pol[h][seg*8];
    }
}

// ----- weight convert: w[k][n] fp32 -> wt[n][k] bf16 (n-major for B-frag) -
__global__ __launch_bounds__(256) void wconv_kernel(const float* __restrict__ wq,
        const float* __restrict__ wk, const float* __restrict__ wv,
        const float* __restrict__ wg, const float* __restrict__ wo,
        unsigned short* __restrict__ wtb, unsigned short* __restrict__ wot) {
    __shared__ float T[64][65];
    const int wi = blockIdx.z;
    const float* W = (wi==0)?wq:(wi==1)?wk:(wi==2)?wv:(wi==3)?wg:wo;
    unsigned short* O = (wi<4) ? (wtb + (size_t)wi*65536) : wot;
    const int bk = blockIdx.x * 64, bn = blockIdx.y * 64;
    const int tx = threadIdx.x & 63, tg = threadIdx.x >> 6;
    #pragma unroll
    for (int i = 0; i < 16; i++) {
        int r = tg*16 + i;
        T[r][tx] = W[(size_t)(bk+r)*256 + bn + tx];
    }
    __syncthreads();
    #pragma unroll
    for (int i = 0; i < 16; i++) {
        int r = tg*16 + i;
        O[(size_t)(bn+r)*256 + bk + tx] = f2bf(T[tx][r]);
    }
}

// ------------- QKVG projection GEMM (MFMA): M=32768, K=256, N=1024 -------
// Staging via async global_load_lds (16B) into unpadded [128][64] tiles.
// Rotation swizzle: LDS slot (r,s) holds global chunk (r,(s+r)&7); frag
// read of global (r,gc) uses slot (gc-r)&7 -> banks = slot*4 only, 2-way.
__global__ __launch_bounds__(256, 3) void qkvg_kernel(
        const unsigned short* __restrict__ snb,
        const unsigned short* __restrict__ wtb,
        const float* __restrict__ bg,
        unsigned short* __restrict__ qo, unsigned short* __restrict__ ko,
        unsigned short* __restrict__ vo, unsigned short* __restrict__ go) {
    __shared__ alignas(16) unsigned short As[128][64];
    __shared__ alignas(16) unsigned short Bs[128][64];
    const int bx = blockIdx.x;
    const int mblk = (bx & 7) * 32 + (bx >> 3);  // XCD-contiguous m-chunks
    const int m0 = mblk * 128;
    const int n0 = blockIdx.y * 128;             // 0..896
    const int seg = n0 >> 8;
    const int nseg = n0 & 255;                   // 0 or 128
    const unsigned short* wt = wtb + (size_t)seg * 65536;
    const int tid = threadIdx.x;
    const int lane = tid & 63, wid = tid >> 6;
    const int ln15 = lane & 15, g = lane >> 4;
    const int wr = wid >> 1, wc = wid & 1;
    f32x4 acc[4][4];
    #pragma unroll
    for (int i = 0; i < 4; i++)
        #pragma unroll
        for (int j = 0; j < 4; j++) acc[i][j] = (f32x4){0.f,0.f,0.f,0.f};

    for (int k0 = 0; k0 < 256; k0 += 64) {
        #pragma unroll
        for (int ci = 0; ci < 4; ci++) {
            int n = tid + ci*256;                // chunk slot 0..1023
            int r = n >> 3, sc = n & 7;
            int gc = (sc + r) & 7;               // global chunk held at slot
            const unsigned short* sA = &snb[(size_t)(m0+r)*256 + k0 + gc*8];
            const unsigned short* sB = &wt[(size_t)(nseg+r)*256 + k0 + gc*8];
            __builtin_amdgcn_global_load_lds(
                (const __attribute__((address_space(1))) unsigned int*)sA,
                (__attribute__((address_space(3))) unsigned int*)(&As[0][0] + (size_t)(wid*64 + ci*256)*8),
                16, 0, 0);
            __builtin_amdgcn_global_load_lds(
                (const __attribute__((address_space(1))) unsigned int*)sB,
                (__attribute__((address_space(3))) unsigned int*)(&Bs[0][0] + (size_t)(wid*64 + ci*256)*8),
                16, 0, 0);
        }
        __syncthreads();
        #pragma unroll
        for (int kk = 0; kk < 64; kk += 32) {
            short8_t a[4], b[4];
            #pragma unroll
            for (int i = 0; i < 4; i++) {
                int ga = (kk >> 3) + g;          // global chunk index
                int ra = wr*64 + i*16 + ln15;
                int rb = wc*64 + i*16 + ln15;
                a[i] = *(const short8_t*)&As[ra][((ga - ra) & 7) * 8];
                b[i] = *(const short8_t*)&Bs[rb][((ga - rb) & 7) * 8];
            }
            #pragma unroll
            for (int i = 0; i < 4; i++)
                #pragma unroll
                for (int j = 0; j < 4; j++)
                    acc[i][j] = __builtin_amdgcn_mfma_f32_16x16x32_bf16(
                                    a[i], b[j], acc[i][j], 0, 0, 0);
        }
        __syncthreads();
    }
    #pragma unroll
    for (int i = 0; i < 4; i++) {
        #pragma unroll
        for (int r = 0; r < 4; r++) {
            int m = m0 + wr*64 + i*16 + g*4 + r;
            int ss = m >> 8, rr = m & 255;
            #pragma unroll
            for (int j = 0; j < 4; j++) {
                int col = n0 + wc*64 + j*16 + ln15;
                int lc = col & 255;
                int h = lc >> 5, d = lc & 31;
                float val = acc[i][j][r];
                size_t qidx = (((size_t)ss*HEADS + h)*RDIM + rr)*DH + d;
                if (seg == 0)      qo[qidx] = f2bf(val * 0.17677669529663687f);
                else if (seg == 1) ko[qidx] = f2bf(val);
                else if (seg == 2) vo[qidx] = f2bf(val);
                else {
                    float x = val + bg[lc];
                    go[(size_t)m*CS + lc] = f2bf(1.f / (1.f + expf(-x)));
                }
            }
        }
    }
}

// ---- attention: swapped-QK^T MFMA flash, block per (s,h), 4 waves -------
// 3 blocks/CU: PBpb LDS buffer removed; pb lives in 16 uint2 regs with a
// same-register reissue pipeline (load qt+1 right after qt's bias consumes
// them; covered by softmax+PV+epilogue+next QK^T). pb buffer is 1MB ->
// L2/L3-resident; strided 8B reads cost cache BW, not HBM.
__global__ __launch_bounds__(256, 3) void attn_kernel(
        const unsigned short* __restrict__ q, const unsigned short* __restrict__ k,
        const unsigned short* __restrict__ v, const unsigned short* __restrict__ pb,
        const float* __restrict__ mask, unsigned short* __restrict__ o) {
    __shared__ alignas(16) unsigned short Klds[256][40];
    __shared__ alignas(16) unsigned short Vtlds[32][264];
    __shared__ alignas(16) unsigned short Plds[4][16][72]; // P / O bounce
    __shared__ float masklds[256];

    const int sh = blockIdx.x;                   // s*8 + h
    const int ss = sh >> 3, h = sh & 7;
    const int tid = threadIdx.x;
    const int lane = tid & 63, wid = tid >> 6;
    const int ln15 = lane & 15, g = lane >> 4;   // g in 0..3

    const unsigned short* kp = k + (size_t)sh * 8192;
    const unsigned short* vp = v + (size_t)sh * 8192;
    const unsigned short* pbh = pb + (size_t)h * ZROWS;
    const unsigned short* pbrow0 = pbh + (size_t)(wid*64 + ln15) * RDIM;

    // ---- issue qt=0 pb loads first (overlap with K/V staging) ----
    uint2 cur[16];
    #pragma unroll
    for (int t = 0; t < 16; t++)
        cur[t] = *(const uint2*)&pbrow0[t*16 + g*4];

    // ---- stage K and V^T to LDS ----
    #pragma unroll
    for (int i = 0; i < 4; i++) {
        int idx = tid + i*256;                   // chunk of 8 bf16, 0..1023
        int row = idx >> 2, col = (idx & 3) * 8; // row: k-index, col: d
        short8_t kv8 = *(const short8_t*)&kp[(size_t)row*DH + col];
        short8_t vv8 = *(const short8_t*)&vp[(size_t)row*DH + col];
        *(short8_t*)&Klds[row][col] = kv8;
        #pragma unroll
        for (int e = 0; e < 8; e++)
            Vtlds[col+e][row] = (unsigned short)vv8[e];
    }
    masklds[tid] = 1e9f * (mask[(size_t)ss*RDIM + tid] - 1.f);

    // ---- Q B-frags for the wave's 4 q-tiles (col=ln15=q, k=g*8 over d) --
    short8_t qfr[4];
    {
        const unsigned short* qp = q + (size_t)sh * 8192;
        #pragma unroll
        for (int qt = 0; qt < 4; qt++)
            qfr[qt] = *(const short8_t*)&qp[(size_t)(wid*64 + qt*16 + ln15)*DH + g*8];
    }
    __syncthreads();

    #pragma unroll 1
    for (int qt = 0; qt < 4; qt++) {
        const int q0 = wid*64 + qt*16;
        // ---- S^T = K . Q^T (LDS deps only; cur loads in flight) ---------
        f32x4 st[16];
        #pragma unroll
        for (int t = 0; t < 16; t++) {
            short8_t kf = *(const short8_t*)&Klds[t*16 + ln15][g*8];
            st[t] = __builtin_amdgcn_mfma_f32_16x16x32_bf16(
                        kf, qfr[qt], (f32x4){0.f,0.f,0.f,0.f}, 0, 0, 0);
        }
        // ---- bias: pb (regs, loaded a full iteration ago) + mask --------
        #pragma unroll
        for (int t = 0; t < 16; t++) {
            float4 mk4 = *(const float4*)&masklds[t*16 + g*4];
            st[t][0] += bflo(cur[t].x) + mk4.x;
            st[t][1] += bfhi(cur[t].x) + mk4.y;
            st[t][2] += bflo(cur[t].y) + mk4.z;
            st[t][3] += bfhi(cur[t].y) + mk4.w;
        }
        // ---- reissue cur <- pb(qt+1): covered until next qt's bias ------
        if (qt < 3) {
            const unsigned short* pbn = pbrow0 + (size_t)(qt+1)*16*RDIM;
            #pragma unroll
            for (int t = 0; t < 16; t++)
                cur[t] = *(const uint2*)&pbn[t*16 + g*4];
        }
        // ---- single-pass softmax, in-lane + 2 shuffles across g ---------
        float mx = -INFINITY;
        #pragma unroll
        for (int t = 0; t < 16; t++) {
            float a = fmaxf(fmaxf(st[t][0], st[t][1]), fmaxf(st[t][2], st[t][3]));
            mx = fmaxf(mx, a);
        }
        mx = fmaxf(mx, __shfl_xor(mx, 16, 64));
        mx = fmaxf(mx, __shfl_xor(mx, 32, 64));
        const float mxl = mx * LOG2E;
        float l = 0.f;
        #pragma unroll
        for (int t = 0; t < 16; t++) {
            #pragma unroll
            for (int r = 0; r < 4; r++) {
                float p = exp2f(fmaf(st[t][r], LOG2E, -mxl));
                st[t][r] = p;
                l += p;
            }
        }
        l += __shfl_xor(l, 16, 64);
        l += __shfl_xor(l, 32, 64);
        float inv = 1.f / l;
        // ---- PV per 64-k chunk: P -> Plds (cvt_pk), O^T += V^T . P^T ----
        f32x4 oacc[2];
        oacc[0] = (f32x4){0.f,0.f,0.f,0.f};
        oacc[1] = (f32x4){0.f,0.f,0.f,0.f};
        #pragma unroll
        for (int c = 0; c < 4; c++) {
            #pragma unroll
            for (int tc = 0; tc < 4; tc++) {
                int t = c*4 + tc;
                uint2 w;
                w.x = cvt_pk_bf16(st[t][0], st[t][1]);
                w.y = cvt_pk_bf16(st[t][2], st[t][3]);
                *(uint2*)&Plds[wid][ln15][tc*16 + g*4] = w;
            }
            #pragma unroll
            for (int ks = 0; ks < 2; ks++) {
                short8_t pfr = *(const short8_t*)&Plds[wid][ln15][ks*32 + g*8];
                #pragma unroll
                for (int dt = 0; dt < 2; dt++) {
                    short8_t vf = *(const short8_t*)&Vtlds[dt*16 + ln15][c*64 + ks*32 + g*8];
                    oacc[dt] = __builtin_amdgcn_mfma_f32_16x16x32_bf16(
                                   vf, pfr, oacc[dt], 0, 0, 0);
                }
            }
        }
        // ---- epilogue: O^T -> Plds [q][d] -> coalesced 16B stores -------
        #pragma unroll
        for (int dt = 0; dt < 2; dt++) {
            uint2 w;
            w.x = cvt_pk_bf16(oacc[dt][0]*inv, oacc[dt][1]*inv);
            w.y = cvt_pk_bf16(oacc[dt][2]*inv, oacc[dt][3]*inv);
            *(uint2*)&Plds[wid][ln15][dt*16 + g*4] = w;
        }
        {
            int qr = lane >> 2, dc = (lane & 3) * 8;
            short8_t ov = *(const short8_t*)&Plds[wid][qr][dc];
            *(short8_t*)&o[((size_t)ss*RDIM + q0 + qr)*CS + h*DH + dc] = ov;
        }
    }
}

// ------------- output projection (MFMA): out = (o .* g) @ wo + bo --------
// B staged via global_load_lds; A (o*g product) reg-staged into the same
// rotation-swizzled [128][64] layout. Frag reads conflict-free (2-way).
__global__ __launch_bounds__(256, 3) void outproj_kernel(
        const unsigned short* __restrict__ ob, const unsigned short* __restrict__ gb,
        const unsigned short* __restrict__ wot, const float* __restrict__ bo,
        float* __restrict__ out) {
    __shared__ alignas(16) unsigned short As[128][64];
    __shared__ alignas(16) unsigned short Bs[128][64];
    const int bx = blockIdx.x;
    const int mblk = (bx & 7) * 32 + (bx >> 3);  // XCD-contiguous m-chunks
    const int m0 = mblk * 128;
    const int n0 = blockIdx.y * 128;             // 0 or 128
    const int tid = threadIdx.x;
    const int lane = tid & 63, wid = tid >> 6;
    const int ln15 = lane & 15, g = lane >> 4;
    const int wr = wid >> 1, wc = wid & 1;
    f32x4 acc[4][4];
    #pragma unroll
    for (int i = 0; i < 4; i++)
        #pragma unroll
        for (int j = 0; j < 4; j++) acc[i][j] = (f32x4){0.f,0.f,0.f,0.f};

    for (int k0 = 0; k0 < 256; k0 += 64) {
        #pragma unroll
        for (int ci = 0; ci < 4; ci++) {
            int n = tid + ci*256;
            int r = n >> 3, sc = n & 7;
            int gcb = (sc + r) & 7;
            const unsigned short* sB = &wot[(size_t)(n0+r)*256 + k0 + gcb*8];
            __builtin_amdgcn_global_load_lds(
                (const __attribute__((address_space(1))) unsigned int*)sB,
                (__attribute__((address_space(3))) unsigned int*)(&Bs[0][0] + (size_t)(wid*64 + ci*256)*8),
                16, 0, 0);
            // A: load global chunk (r, sc-as-gc), compute o*g, store swizzled
            int row = r, gc = sc;
            short8_t ov = *(const short8_t*)&ob[(size_t)(m0+row)*256 + k0 + gc*8];
            short8_t gv = *(const short8_t*)&gb[(size_t)(m0+row)*256 + k0 + gc*8];
            unsigned pr[4];
            #pragma unroll
            for (int e = 0; e < 4; e++) {
                float p0 = bf2f((unsigned short)ov[e*2+0]) * bf2f((unsigned short)gv[e*2+0]);
                float p1 = bf2f((unsigned short)ov[e*2+1]) * bf2f((unsigned short)gv[e*2+1]);
                pr[e] = cvt_pk_bf16(p0, p1);
            }
            *(uint4*)&As[row][((gc - row) & 7) * 8] = *(uint4*)pr;
        }
        __syncthreads();
        #pragma unroll
        for (int kk = 0; kk < 64; kk += 32) {
            short8_t a[4], b[4];
            #pragma unroll
            for (int i = 0; i < 4; i++) {
                int ga = (kk >> 3) + g;
                int ra = wr*64 + i*16 + ln15;
                int rb = wc*64 + i*16 + ln15;
                a[i] = *(const short8_t*)&As[ra][((ga - ra) & 7) * 8];
                b[i] = *(const short8_t*)&Bs[rb][((ga - rb) & 7) * 8];
            }
            #pragma unroll
            for (int i = 0; i < 4; i++)
                #pragma unroll
                for (int j = 0; j < 4; j++)
                    acc[i][j] = __builtin_amdgcn_mfma_f32_16x16x32_bf16(
                                    a[i], b[j], acc[i][j], 0, 0, 0);
        }
        __syncthreads();
    }
    #pragma unroll
    for (int i = 0; i < 4; i++) {
        #pragma unroll
        for (int r = 0; r < 4; r++) {
            int m = m0 + wr*64 + i*16 + g*4 + r;
            #pragma unroll
            for (int j = 0; j < 4; j++) {
                int col = n0 + wc*64 + j*16 + ln15;
                out[(size_t)m*CS + col] = acc[i][j][r] + bo[col];
            }
        }
    }
}

extern "C" void kernel_launch(void* const* d_in, const int* in_sizes, int n_in,
                              void* d_out, int out_size, void* d_ws, size_t ws_size,
                              hipStream_t stream) {
    const float* s      = (const float*)d_in[0];
    const float* z      = (const float*)d_in[1];
    const float* mask   = (const float*)d_in[2];
    const float* ln_s_w = (const float*)d_in[3];
    const float* ln_s_b = (const float*)d_in[4];
    const float* ln_z_w = (const float*)d_in[5];
    const float* ln_z_b = (const float*)d_in[6];
    const float* w_z    = (const float*)d_in[7];
    const float* w_q    = (const float*)d_in[8];
    const float* w_k    = (const float*)d_in[9];
    const float* w_v    = (const float*)d_in[10];
    const float* w_g    = (const float*)d_in[11];
    const float* b_g    = (const float*)d_in[12];
    const float* w_o    = (const float*)d_in[13];
    const float* b_o    = (const float*)d_in[14];
    float* out = (float*)d_out;
    float* ws  = (float*)d_ws;

    // Workspace layout (float units; bf16 buffers cast):
    unsigned short* snb = (unsigned short*)ws;                    // 8388608 shorts
    unsigned short* wtb = (unsigned short*)(ws + 4194304);        // 262144 shorts
    unsigned short* wot = (unsigned short*)(ws + 4194304+131072); // 65536 shorts
    unsigned short* pbb = (unsigned short*)(ws + 4194304+131072+32768); // 524288 shorts (bf16)
    float* after_pb = ws + 4194304 + 131072 + 32768 + 262144;
    unsigned short* qb  = (unsigned short*)after_pb;              // 8388608 shorts each
    unsigned short* kb  = qb + 8388608;
    unsigned short* vb  = kb + 8388608;
    unsigned short* gbuf= vb + 8388608;
    unsigned short* obuf= gbuf + 8388608;

    ln_s_kernel<<<MROWS/4, 256, 0, stream>>>(s, ln_s_w, ln_s_b, snb);
    ln_z_pb_kernel<<<ZROWS/64, 256, 0, stream>>>(z, ln_z_w, ln_z_b, w_z, pbb);
    wconv_kernel<<<dim3(4,4,5), 256, 0, stream>>>(w_q, w_k, w_v, w_g, w_o, wtb, wot);
    qkvg_kernel<<<dim3(MROWS/128, 8), 256, 0, stream>>>(snb, wtb, b_g, qb, kb, vb, gbuf);
    attn_kernel<<<SDIM*HEADS, 256, 0, stream>>>(qb, kb, vb, pbb, mask, obuf);
    outproj_kernel<<<dim3(MROWS/128, 2), 256, 0, stream>>>(obuf, gbuf, wot, b_o, out);
}

// Round 18
// 142.152 us; speedup vs baseline: 1.7299x; 1.7299x over previous
//
#include <hip/hip_runtime.h>
#include <math.h>

#define CS 256
#define CZ 128
#define HEADS 8
#define DH 32
#define SDIM 128
#define RDIM 256
#define MROWS (SDIM*RDIM)   // 32768
#define ZROWS (RDIM*RDIM)   // 65536
#define EPSF 1e-5f
#define LOG2E 1.44269504088896340736f

typedef __attribute__((ext_vector_type(8))) short short8_t;   // 8 bf16 (4 VGPRs)
typedef __attribute__((ext_vector_type(4))) float f32x4;

__device__ __forceinline__ float waveReduceSum(float v) {
    #pragma unroll
    for (int off = 32; off > 0; off >>= 1) v += __shfl_xor(v, off, 64);
    return v;
}

__device__ __forceinline__ unsigned short f2bf(float f) {
    unsigned u = __float_as_uint(f);
    unsigned r = (u + 0x7fffu + ((u >> 16) & 1u)) >> 16;   // RNE
    return (unsigned short)r;
}

__device__ __forceinline__ float bf2f(unsigned short u) {
    return __uint_as_float(((unsigned)u) << 16);
}

// fast packed-bf16 -> f32 unpack (1 op each)
__device__ __forceinline__ float bflo(unsigned u) { return __uint_as_float(u << 16); }
__device__ __forceinline__ float bfhi(unsigned u) { return __uint_as_float(u & 0xffff0000u); }

// packed bf16 convert: lo = a, hi = b (HW RNE, 1 instruction)
__device__ __forceinline__ unsigned cvt_pk_bf16(float a, float b) {
    unsigned r;
    asm("v_cvt_pk_bf16_f32 %0, %1, %2" : "=v"(r) : "v"(a), "v"(b));
    return r;
}

// ---------------- LayerNorm of s: one wave per row of 256, bf16 out ------
__global__ __launch_bounds__(256) void ln_s_kernel(const float* __restrict__ s,
        const float* __restrict__ w, const float* __restrict__ b,
        unsigned short* __restrict__ snb) {
    int wid = threadIdx.x >> 6;
    int lane = threadIdx.x & 63;
    int row = blockIdx.x * 4 + wid;              // < 32768
    const float4 v = ((const float4*)(s + (size_t)row * CS))[lane];
    float sum = waveReduceSum(v.x + v.y + v.z + v.w);
    float sq  = waveReduceSum(v.x*v.x + v.y*v.y + v.z*v.z + v.w*v.w);
    float mean = sum * (1.f/CS);
    float var  = sq * (1.f/CS) - mean*mean;
    float rstd = rsqrtf(var + EPSF);
    const float4 wv = ((const float4*)w)[lane];
    const float4 bv = ((const float4*)b)[lane];
    ushort4 o;
    o.x = f2bf((v.x-mean)*rstd*wv.x + bv.x);
    o.y = f2bf((v.y-mean)*rstd*wv.y + bv.y);
    o.z = f2bf((v.z-mean)*rstd*wv.z + bv.z);
    o.w = f2bf((v.w-mean)*rstd*wv.w + bv.w);
    ((ushort4*)(snb + (size_t)row * CS))[lane] = o;
}

// ------- LayerNorm of z + pair bias via MFMA: block = 64 z-rows ----------
__global__ __launch_bounds__(256) void ln_z_pb_kernel(const float* __restrict__ z,
        const float* __restrict__ w, const float* __restrict__ b,
        const float* __restrict__ wz, unsigned short* __restrict__ pb) {
    __shared__ unsigned short Pol[8][64];
    const int tid = threadIdx.x;
    const int lane = tid & 63, wid = tid >> 6;
    const int ln15 = lane & 15, g = lane >> 4;
    const int base = blockIdx.x * 64;
    const int row = base + wid*16 + ln15;
    const float* zr = z + (size_t)row * CZ;

    // ---- A-frags: wz^T bf16 (row=h=ln15, zero for h>=8) ----
    short8_t wzf[4];
    #pragma unroll
    for (int kk = 0; kk < 4; kk++) {
        short8_t f;
        #pragma unroll
        for (int j = 0; j < 8; j++) {
            float vv = (ln15 < 8) ? wz[(size_t)(kk*32 + g*8 + j)*HEADS + ln15] : 0.f;
            f[j] = (short)f2bf(vv);
        }
        wzf[kk] = f;
    }
    // ---- load z (full-line: 4 g-lanes cover 128B per (row,kk)) ----
    float zv[4][8];
    float sum = 0.f, sq = 0.f;
    #pragma unroll
    for (int kk = 0; kk < 4; kk++) {
        float4 a0 = *(const float4*)&zr[kk*32 + g*8];
        float4 a1 = *(const float4*)&zr[kk*32 + g*8 + 4];
        zv[kk][0]=a0.x; zv[kk][1]=a0.y; zv[kk][2]=a0.z; zv[kk][3]=a0.w;
        zv[kk][4]=a1.x; zv[kk][5]=a1.y; zv[kk][6]=a1.z; zv[kk][7]=a1.w;
        #pragma unroll
        for (int j = 0; j < 8; j++) { sum += zv[kk][j]; sq = fmaf(zv[kk][j], zv[kk][j], sq); }
    }
    sum += __shfl_xor(sum, 16, 64); sum += __shfl_xor(sum, 32, 64);
    sq  += __shfl_xor(sq, 16, 64);  sq  += __shfl_xor(sq, 32, 64);
    float mean = sum * (1.f/CZ);
    float var  = sq * (1.f/CZ) - mean*mean;
    float rstd = rsqrtf(var + EPSF);
    float mr = mean * rstd;
    // ---- zn B-frags (col=ln15=row-idx, k=g*8.. within each kk) ----
    short8_t znf[4];
    #pragma unroll
    for (int kk = 0; kk < 4; kk++) {
        float4 w0 = *(const float4*)&w[kk*32 + g*8];
        float4 w1 = *(const float4*)&w[kk*32 + g*8 + 4];
        float4 b0 = *(const float4*)&b[kk*32 + g*8];
        float4 b1 = *(const float4*)&b[kk*32 + g*8 + 4];
        float wl[8] = {w0.x,w0.y,w0.z,w0.w,w1.x,w1.y,w1.z,w1.w};
        float bl[8] = {b0.x,b0.y,b0.z,b0.w,b1.x,b1.y,b1.z,b1.w};
        unsigned pk[4];
        #pragma unroll
        for (int e = 0; e < 4; e++) {
            float n0 = fmaf(fmaf(zv[kk][e*2+0], rstd, -mr), wl[e*2+0], bl[e*2+0]);
            float n1 = fmaf(fmaf(zv[kk][e*2+1], rstd, -mr), wl[e*2+1], bl[e*2+1]);
            pk[e] = cvt_pk_bf16(n0, n1);
        }
        znf[kk] = *(short8_t*)pk;
    }
    // ---- pb = wz^T . zn^T ----
    f32x4 acc = (f32x4){0.f,0.f,0.f,0.f};
    #pragma unroll
    for (int kk = 0; kk < 4; kk++)
        acc = __builtin_amdgcn_mfma_f32_16x16x32_bf16(wzf[kk], znf[kk], acc, 0, 0, 0);
    // ---- bounce to LDS, coalesced store: pb[h][base..base+63] ----
    if (g < 2) {
        #pragma unroll
        for (int r = 0; r < 4; r++)
            Pol[g*4 + r][wid*16 + ln15] = f2bf(acc[r]);
    }
    __syncthreads();
    if (tid < 64) {
        int h = tid >> 3, seg = tid & 7;
        *(uint4*)&pb[(size_t)h*ZROWS + base + seg*8] = *(uint4*)&Pol[h][seg*8];
    }
}

// ----- weight convert: w[k][n] fp32 -> wt[n][k] bf16 (n-major for B-frag) -
__global__ __launch_bounds__(256) void wconv_kernel(const float* __restrict__ wq,
        const float* __restrict__ wk, const float* __restrict__ wv,
        const float* __restrict__ wg, const float* __restrict__ wo,
        unsigned short* __restrict__ wtb, unsigned short* __restrict__ wot) {
    __shared__ float T[64][65];
    const int wi = blockIdx.z;
    const float* W = (wi==0)?wq:(wi==1)?wk:(wi==2)?wv:(wi==3)?wg:wo;
    unsigned short* O = (wi<4) ? (wtb + (size_t)wi*65536) : wot;
    const int bk = blockIdx.x * 64, bn = blockIdx.y * 64;
    const int tx = threadIdx.x & 63, tg = threadIdx.x >> 6;
    #pragma unroll
    for (int i = 0; i < 16; i++) {
        int r = tg*16 + i;
        T[r][tx] = W[(size_t)(bk+r)*256 + bn + tx];
    }
    __syncthreads();
    #pragma unroll
    for (int i = 0; i < 16; i++) {
        int r = tg*16 + i;
        O[(size_t)(bn+r)*256 + bk + tx] = f2bf(T[tx][r]);
    }
}

// ------------- QKVG projection GEMM (MFMA): M=32768, K=256, N=1024 -------
// Staging via async global_load_lds (16B) into unpadded [128][64] tiles.
// Rotation swizzle: LDS slot (r,s) holds global chunk (r,(s+r)&7); frag
// read of global (r,gc) uses slot (gc-r)&7 -> banks = slot*4 only, 2-way.
__global__ __launch_bounds__(256, 3) void qkvg_kernel(
        const unsigned short* __restrict__ snb,
        const unsigned short* __restrict__ wtb,
        const float* __restrict__ bg,
        unsigned short* __restrict__ qo, unsigned short* __restrict__ ko,
        unsigned short* __restrict__ vo, unsigned short* __restrict__ go) {
    __shared__ alignas(16) unsigned short As[128][64];
    __shared__ alignas(16) unsigned short Bs[128][64];
    const int bx = blockIdx.x;
    const int mblk = (bx & 7) * 32 + (bx >> 3);  // XCD-contiguous m-chunks
    const int m0 = mblk * 128;
    const int n0 = blockIdx.y * 128;             // 0..896
    const int seg = n0 >> 8;
    const int nseg = n0 & 255;                   // 0 or 128
    const unsigned short* wt = wtb + (size_t)seg * 65536;
    const int tid = threadIdx.x;
    const int lane = tid & 63, wid = tid >> 6;
    const int ln15 = lane & 15, g = lane >> 4;
    const int wr = wid >> 1, wc = wid & 1;
    f32x4 acc[4][4];
    #pragma unroll
    for (int i = 0; i < 4; i++)
        #pragma unroll
        for (int j = 0; j < 4; j++) acc[i][j] = (f32x4){0.f,0.f,0.f,0.f};

    for (int k0 = 0; k0 < 256; k0 += 64) {
        #pragma unroll
        for (int ci = 0; ci < 4; ci++) {
            int n = tid + ci*256;                // chunk slot 0..1023
            int r = n >> 3, sc = n & 7;
            int gc = (sc + r) & 7;               // global chunk held at slot
            const unsigned short* sA = &snb[(size_t)(m0+r)*256 + k0 + gc*8];
            const unsigned short* sB = &wt[(size_t)(nseg+r)*256 + k0 + gc*8];
            __builtin_amdgcn_global_load_lds(
                (const __attribute__((address_space(1))) unsigned int*)sA,
                (__attribute__((address_space(3))) unsigned int*)(&As[0][0] + (size_t)(wid*64 + ci*256)*8),
                16, 0, 0);
            __builtin_amdgcn_global_load_lds(
                (const __attribute__((address_space(1))) unsigned int*)sB,
                (__attribute__((address_space(3))) unsigned int*)(&Bs[0][0] + (size_t)(wid*64 + ci*256)*8),
                16, 0, 0);
        }
        __syncthreads();
        #pragma unroll
        for (int kk = 0; kk < 64; kk += 32) {
            short8_t a[4], b[4];
            #pragma unroll
            for (int i = 0; i < 4; i++) {
                int ga = (kk >> 3) + g;          // global chunk index
                int ra = wr*64 + i*16 + ln15;
                int rb = wc*64 + i*16 + ln15;
                a[i] = *(const short8_t*)&As[ra][((ga - ra) & 7) * 8];
                b[i] = *(const short8_t*)&Bs[rb][((ga - rb) & 7) * 8];
            }
            #pragma unroll
            for (int i = 0; i < 4; i++)
                #pragma unroll
                for (int j = 0; j < 4; j++)
                    acc[i][j] = __builtin_amdgcn_mfma_f32_16x16x32_bf16(
                                    a[i], b[j], acc[i][j], 0, 0, 0);
        }
        __syncthreads();
    }
    #pragma unroll
    for (int i = 0; i < 4; i++) {
        #pragma unroll
        for (int r = 0; r < 4; r++) {
            int m = m0 + wr*64 + i*16 + g*4 + r;
            int ss = m >> 8, rr = m & 255;
            #pragma unroll
            for (int j = 0; j < 4; j++) {
                int col = n0 + wc*64 + j*16 + ln15;
                int lc = col & 255;
                int h = lc >> 5, d = lc & 31;
                float val = acc[i][j][r];
                size_t qidx = (((size_t)ss*HEADS + h)*RDIM + rr)*DH + d;
                if (seg == 0)      qo[qidx] = f2bf(val * 0.17677669529663687f);
                else if (seg == 1) ko[qidx] = f2bf(val);
                else if (seg == 2) vo[qidx] = f2bf(val);
                else {
                    float x = val + bg[lc];
                    go[(size_t)m*CS + lc] = f2bf(1.f / (1.f + expf(-x)));
                }
            }
        }
    }
}

// ---- attention: swapped-QK^T MFMA flash, block per (s,h), 4 waves -------
// REVERTED to the 62-us r15/r16-benched config: pb staged via async
// global_load_lds into per-wave PBpb (both-sides XOR chunk swizzle),
// 2 blocks/CU, 88 VGPR (no spills). cvt_pk packs, Plds P/O bounce.
__global__ __launch_bounds__(256, 2) void attn_kernel(
        const unsigned short* __restrict__ q, const unsigned short* __restrict__ k,
        const unsigned short* __restrict__ v, const unsigned short* __restrict__ pb,
        const float* __restrict__ mask, unsigned short* __restrict__ o) {
    __shared__ alignas(16) unsigned short Klds[256][40];
    __shared__ alignas(16) unsigned short Vtlds[32][264];
    __shared__ alignas(16) unsigned short PBpb[4][4096];   // per-wave pb tile (swizzled)
    __shared__ alignas(16) unsigned short Plds[4][16][72]; // P / O bounce
    __shared__ float masklds[256];

    const int sh = blockIdx.x;                   // s*8 + h
    const int ss = sh >> 3, h = sh & 7;
    const int tid = threadIdx.x;
    const int lane = tid & 63, wid = tid >> 6;
    const int ln15 = lane & 15, g = lane >> 4;   // g in 0..3

    const unsigned short* kp = k + (size_t)sh * 8192;
    const unsigned short* vp = v + (size_t)sh * 8192;
    const unsigned short* pbh = pb + (size_t)h * ZROWS;
    unsigned short* pbw = &PBpb[wid][0];

    // ---- async-stage pb tile qt=0 (before K/V staging: long cover) ------
    {
        const unsigned short* pbase = pbh + (size_t)(wid*64) * RDIM;
        #pragma unroll
        for (int j = 0; j < 8; j++) {
            int w = j*64 + lane;
            int n = w ^ ((w >> 5) & 7);          // involution chunk swizzle
            const unsigned short* src = pbase + (n >> 5) * RDIM + (n & 31) * 8;
            __builtin_amdgcn_global_load_lds(
                (const __attribute__((address_space(1))) unsigned int*)src,
                (__attribute__((address_space(3))) unsigned int*)(pbw + j*512),
                16, 0, 0);
        }
    }

    // ---- stage K and V^T to LDS ----
    #pragma unroll
    for (int i = 0; i < 4; i++) {
        int idx = tid + i*256;                   // chunk of 8 bf16, 0..1023
        int row = idx >> 2, col = (idx & 3) * 8; // row: k-index, col: d
        short8_t kv8 = *(const short8_t*)&kp[(size_t)row*DH + col];
        short8_t vv8 = *(const short8_t*)&vp[(size_t)row*DH + col];
        *(short8_t*)&Klds[row][col] = kv8;
        #pragma unroll
        for (int e = 0; e < 8; e++)
            Vtlds[col+e][row] = (unsigned short)vv8[e];
    }
    masklds[tid] = 1e9f * (mask[(size_t)ss*RDIM + tid] - 1.f);

    // ---- Q B-frags for the wave's 4 q-tiles (col=ln15=q, k=g*8 over d) --
    short8_t qfr[4];
    {
        const unsigned short* qp = q + (size_t)sh * 8192;
        #pragma unroll
        for (int qt = 0; qt < 4; qt++)
            qfr[qt] = *(const short8_t*)&qp[(size_t)(wid*64 + qt*16 + ln15)*DH + g*8];
    }
    __syncthreads();

    #pragma unroll 1
    for (int qt = 0; qt < 4; qt++) {
        const int q0 = wid*64 + qt*16;
        // ---- S^T = K . Q^T (LDS deps only; pb gll still in flight) ------
        f32x4 st[16];
        #pragma unroll
        for (int t = 0; t < 16; t++) {
            short8_t kf = *(const short8_t*)&Klds[t*16 + ln15][g*8];
            st[t] = __builtin_amdgcn_mfma_f32_16x16x32_bf16(
                        kf, qfr[qt], (f32x4){0.f,0.f,0.f,0.f}, 0, 0, 0);
        }
        // ---- pb landed? then bias: pb (swizzled LDS) + mask (bcast) -----
        asm volatile("s_waitcnt vmcnt(0)" ::: "memory");
        __builtin_amdgcn_sched_barrier(0);
        #pragma unroll
        for (int t = 0; t < 16; t++) {
            int n = ln15*32 + t*2 + (g >> 1);
            int m = n ^ (ln15 & 7);
            uint2 p2 = *(const uint2*)&pbw[m*8 + (g & 1)*4];
            float4 mk4 = *(const float4*)&masklds[t*16 + g*4];
            st[t][0] += bflo(p2.x) + mk4.x;
            st[t][1] += bfhi(p2.x) + mk4.y;
            st[t][2] += bflo(p2.y) + mk4.z;
            st[t][3] += bfhi(p2.y) + mk4.w;
        }
        // ---- single-pass softmax, in-lane + 2 shuffles across g ---------
        float mx = -INFINITY;
        #pragma unroll
        for (int t = 0; t < 16; t++) {
            float a = fmaxf(fmaxf(st[t][0], st[t][1]), fmaxf(st[t][2], st[t][3]));
            mx = fmaxf(mx, a);
        }
        mx = fmaxf(mx, __shfl_xor(mx, 16, 64));
        mx = fmaxf(mx, __shfl_xor(mx, 32, 64));
        const float mxl = mx * LOG2E;
        float l = 0.f;
        #pragma unroll
        for (int t = 0; t < 16; t++) {
            #pragma unroll
            for (int r = 0; r < 4; r++) {
                float p = exp2f(fmaf(st[t][r], LOG2E, -mxl));
                st[t][r] = p;
                l += p;
            }
        }
        l += __shfl_xor(l, 16, 64);
        l += __shfl_xor(l, 32, 64);
        float inv = 1.f / l;
        // ---- issue next tile's pb gll (buffer free; covers under PV) ----
        if (qt < 3) {
            const unsigned short* pbase = pbh + (size_t)(q0 + 16) * RDIM;
            #pragma unroll
            for (int j = 0; j < 8; j++) {
                int w = j*64 + lane;
                int n = w ^ ((w >> 5) & 7);
                const unsigned short* src = pbase + (n >> 5) * RDIM + (n & 31) * 8;
                __builtin_amdgcn_global_load_lds(
                    (const __attribute__((address_space(1))) unsigned int*)src,
                    (__attribute__((address_space(3))) unsigned int*)(pbw + j*512),
                    16, 0, 0);
            }
        }
        // ---- PV per 64-k chunk: P -> Plds (cvt_pk), O^T += V^T . P^T ----
        f32x4 oacc[2];
        oacc[0] = (f32x4){0.f,0.f,0.f,0.f};
        oacc[1] = (f32x4){0.f,0.f,0.f,0.f};
        #pragma unroll
        for (int c = 0; c < 4; c++) {
            #pragma unroll
            for (int tc = 0; tc < 4; tc++) {
                int t = c*4 + tc;
                uint2 w;
                w.x = cvt_pk_bf16(st[t][0], st[t][1]);
                w.y = cvt_pk_bf16(st[t][2], st[t][3]);
                *(uint2*)&Plds[wid][ln15][tc*16 + g*4] = w;
            }
            #pragma unroll
            for (int ks = 0; ks < 2; ks++) {
                short8_t pfr = *(const short8_t*)&Plds[wid][ln15][ks*32 + g*8];
                #pragma unroll
                for (int dt = 0; dt < 2; dt++) {
                    short8_t vf = *(const short8_t*)&Vtlds[dt*16 + ln15][c*64 + ks*32 + g*8];
                    oacc[dt] = __builtin_amdgcn_mfma_f32_16x16x32_bf16(
                                   vf, pfr, oacc[dt], 0, 0, 0);
                }
            }
        }
        // ---- epilogue: O^T -> Plds [q][d] -> coalesced 16B stores -------
        #pragma unroll
        for (int dt = 0; dt < 2; dt++) {
            uint2 w;
            w.x = cvt_pk_bf16(oacc[dt][0]*inv, oacc[dt][1]*inv);
            w.y = cvt_pk_bf16(oacc[dt][2]*inv, oacc[dt][3]*inv);
            *(uint2*)&Plds[wid][ln15][dt*16 + g*4] = w;
        }
        {
            int qr = lane >> 2, dc = (lane & 3) * 8;
            short8_t ov = *(const short8_t*)&Plds[wid][qr][dc];
            *(short8_t*)&o[((size_t)ss*RDIM + q0 + qr)*CS + h*DH + dc] = ov;
        }
    }
}

// ------------- output projection (MFMA): out = (o .* g) @ wo + bo --------
// B staged via global_load_lds; A (o*g product) reg-staged into the same
// rotation-swizzled [128][64] layout. Frag reads conflict-free (2-way).
__global__ __launch_bounds__(256, 3) void outproj_kernel(
        const unsigned short* __restrict__ ob, const unsigned short* __restrict__ gb,
        const unsigned short* __restrict__ wot, const float* __restrict__ bo,
        float* __restrict__ out) {
    __shared__ alignas(16) unsigned short As[128][64];
    __shared__ alignas(16) unsigned short Bs[128][64];
    const int bx = blockIdx.x;
    const int mblk = (bx & 7) * 32 + (bx >> 3);  // XCD-contiguous m-chunks
    const int m0 = mblk * 128;
    const int n0 = blockIdx.y * 128;             // 0 or 128
    const int tid = threadIdx.x;
    const int lane = tid & 63, wid = tid >> 6;
    const int ln15 = lane & 15, g = lane >> 4;
    const int wr = wid >> 1, wc = wid & 1;
    f32x4 acc[4][4];
    #pragma unroll
    for (int i = 0; i < 4; i++)
        #pragma unroll
        for (int j = 0; j < 4; j++) acc[i][j] = (f32x4){0.f,0.f,0.f,0.f};

    for (int k0 = 0; k0 < 256; k0 += 64) {
        #pragma unroll
        for (int ci = 0; ci < 4; ci++) {
            int n = tid + ci*256;
            int r = n >> 3, sc = n & 7;
            int gcb = (sc + r) & 7;
            const unsigned short* sB = &wot[(size_t)(n0+r)*256 + k0 + gcb*8];
            __builtin_amdgcn_global_load_lds(
                (const __attribute__((address_space(1))) unsigned int*)sB,
                (__attribute__((address_space(3))) unsigned int*)(&Bs[0][0] + (size_t)(wid*64 + ci*256)*8),
                16, 0, 0);
            // A: load global chunk (r, sc-as-gc), compute o*g, store swizzled
            int row = r, gc = sc;
            short8_t ov = *(const short8_t*)&ob[(size_t)(m0+row)*256 + k0 + gc*8];
            short8_t gv = *(const short8_t*)&gb[(size_t)(m0+row)*256 + k0 + gc*8];
            unsigned pr[4];
            #pragma unroll
            for (int e = 0; e < 4; e++) {
                float p0 = bf2f((unsigned short)ov[e*2+0]) * bf2f((unsigned short)gv[e*2+0]);
                float p1 = bf2f((unsigned short)ov[e*2+1]) * bf2f((unsigned short)gv[e*2+1]);
                pr[e] = cvt_pk_bf16(p0, p1);
            }
            *(uint4*)&As[row][((gc - row) & 7) * 8] = *(uint4*)pr;
        }
        __syncthreads();
        #pragma unroll
        for (int kk = 0; kk < 64; kk += 32) {
            short8_t a[4], b[4];
            #pragma unroll
            for (int i = 0; i < 4; i++) {
                int ga = (kk >> 3) + g;
                int ra = wr*64 + i*16 + ln15;
                int rb = wc*64 + i*16 + ln15;
                a[i] = *(const short8_t*)&As[ra][((ga - ra) & 7) * 8];
                b[i] = *(const short8_t*)&Bs[rb][((ga - rb) & 7) * 8];
            }
            #pragma unroll
            for (int i = 0; i < 4; i++)
                #pragma unroll
                for (int j = 0; j < 4; j++)
                    acc[i][j] = __builtin_amdgcn_mfma_f32_16x16x32_bf16(
                                    a[i], b[j], acc[i][j], 0, 0, 0);
        }
        __syncthreads();
    }
    #pragma unroll
    for (int i = 0; i < 4; i++) {
        #pragma unroll
        for (int r = 0; r < 4; r++) {
            int m = m0 + wr*64 + i*16 + g*4 + r;
            #pragma unroll
            for (int j = 0; j < 4; j++) {
                int col = n0 + wc*64 + j*16 + ln15;
                out[(size_t)m*CS + col] = acc[i][j][r] + bo[col];
            }
        }
    }
}

extern "C" void kernel_launch(void* const* d_in, const int* in_sizes, int n_in,
                              void* d_out, int out_size, void* d_ws, size_t ws_size,
                              hipStream_t stream) {
    const float* s      = (const float*)d_in[0];
    const float* z      = (const float*)d_in[1];
    const float* mask   = (const float*)d_in[2];
    const float* ln_s_w = (const float*)d_in[3];
    const float* ln_s_b = (const float*)d_in[4];
    const float* ln_z_w = (const float*)d_in[5];
    const float* ln_z_b = (const float*)d_in[6];
    const float* w_z    = (const float*)d_in[7];
    const float* w_q    = (const float*)d_in[8];
    const float* w_k    = (const float*)d_in[9];
    const float* w_v    = (const float*)d_in[10];
    const float* w_g    = (const float*)d_in[11];
    const float* b_g    = (const float*)d_in[12];
    const float* w_o    = (const float*)d_in[13];
    const float* b_o    = (const float*)d_in[14];
    float* out = (float*)d_out;
    float* ws  = (float*)d_ws;

    // Workspace layout (float units; bf16 buffers cast):
    unsigned short* snb = (unsigned short*)ws;                    // 8388608 shorts
    unsigned short* wtb = (unsigned short*)(ws + 4194304);        // 262144 shorts
    unsigned short* wot = (unsigned short*)(ws + 4194304+131072); // 65536 shorts
    unsigned short* pbb = (unsigned short*)(ws + 4194304+131072+32768); // 524288 shorts (bf16)
    float* after_pb = ws + 4194304 + 131072 + 32768 + 262144;
    unsigned short* qb  = (unsigned short*)after_pb;              // 8388608 shorts each
    unsigned short* kb  = qb + 8388608;
    unsigned short* vb  = kb + 8388608;
    unsigned short* gbuf= vb + 8388608;
    unsigned short* obuf= gbuf + 8388608;

    ln_s_kernel<<<MROWS/4, 256, 0, stream>>>(s, ln_s_w, ln_s_b, snb);
    ln_z_pb_kernel<<<ZROWS/64, 256, 0, stream>>>(z, ln_z_w, ln_z_b, w_z, pbb);
    wconv_kernel<<<dim3(4,4,5), 256, 0, stream>>>(w_q, w_k, w_v, w_g, w_o, wtb, wot);
    qkvg_kernel<<<dim3(MROWS/128, 8), 256, 0, stream>>>(snb, wtb, b_g, qb, kb, vb, gbuf);
    attn_kernel<<<SDIM*HEADS, 256, 0, stream>>>(qb, kb, vb, pbb, mask, obuf);
    outproj_kernel<<<dim3(MROWS/128, 2), 256, 0, stream>>>(obuf, gbuf, wot, b_o, out);
}